// Round 3
// baseline (352.644 us; speedup 1.0000x reference)
//
#include <hip/hip_runtime.h>
#include <hip/hip_cooperative_groups.h>
#include <math.h>

namespace cg = cooperative_groups;

#define NQ   1280
#define DD   256
#define CIN  64
#define HH   200
#define WW   200
#define BB   8
#define KW   576                 // CIN * 9 taps per output channel
#define GRID 512                 // BB * 64
#define TPB  256
#define NTH  (GRID * TPB)        // 131072 threads
#define TOTAL4 (BB * NQ * DD / 4)  // 655360 float4 of output

__device__ __forceinline__ float wave_reduce(float v) {
#pragma unroll
    for (int off = 32; off > 0; off >>= 1) v += __shfl_down(v, off, 64);
    return v;
}

// Single cooperative kernel, 3 phases separated by grid.sync():
//  P1: s[b,c] = bilinear blend of ReLU(conv3x3(bev)[c]) at per-batch point;
//      aws[b] = sineembed(point_score[b]) . aws_w + aws_b
//  P2: t[b,d] = aws[b] * dot(out_w[d,:], s[b,:]) + out_b[d]
//  P3: out[b,q,:] = queries[b,q,:] + t[b,:]
__global__ __launch_bounds__(256) void fused_kernel(
    const float* __restrict__ navi,    // (B,2)
    const float* __restrict__ bev,     // (B,64,H,W)
    const float* __restrict__ pscore,  // (B,2)
    const float* __restrict__ aws_w,   // (256,)
    const float* __restrict__ aws_b,   // (1,)
    const float* __restrict__ conv_w,  // (256,64,3,3)
    const float* __restrict__ conv_b,  // (256,)
    const float* __restrict__ out_w,   // (256,256)
    const float* __restrict__ out_b,   // (256,)
    const float4* __restrict__ q4,     // queries as float4
    float4* __restrict__ out4,         // output as float4
    float* __restrict__ s_g,           // ws: (B,256)
    float* __restrict__ aws_g,         // ws: (B,)
    float* __restrict__ t_g)           // ws: (B,256)
{
    cg::grid_group grid = cg::this_grid();
    const int b    = blockIdx.x >> 6;
    const int cgp  = blockIdx.x & 63;
    const int tid  = threadIdx.x;
    const int lane = tid & 63;
    const int wave = tid >> 6;

    __shared__ float win[CIN * 16];  // 4x4 zero-padded window per in-channel
    __shared__ float red[DD];        // aws reduction / s staging (reused)

    // ================= Phase 1: conv + bilinear sample =================
    {
        float nx = navi[b * 2 + 0];
        float ny = navi[b * 2 + 1];
        float gx = (ny * (1.0f / 32.0f) + 1.0f) * 0.5f * (float)WW - 0.5f;
        float gy = (nx * (1.0f / 32.0f) + 1.0f) * 0.5f * (float)HH - 0.5f;
        float x0f = floorf(gx), y0f = floorf(gy);
        float wx1 = gx - x0f, wy1 = gy - y0f;
        int x0 = (int)x0f, y0 = (int)y0f;

        float cw[4];
        {
            float wx[2] = {1.0f - wx1, wx1};
            float wy[2] = {1.0f - wy1, wy1};
#pragma unroll
            for (int k = 0; k < 4; ++k) {
                int dx = k & 1, dy = k >> 1;
                float ixf = x0f + (float)dx, iyf = y0f + (float)dy;
                bool valid = (ixf >= 0.0f) && (ixf <= (float)(WW - 1)) &&
                             (iyf >= 0.0f) && (iyf <= (float)(HH - 1));
                cw[k] = wx[dx] * wy[dy] * (valid ? 1.0f : 0.0f);
            }
        }

        // stage 4x4 zero-padded window for all 64 input channels
        for (int idx = tid; idx < CIN * 16; idx += TPB) {
            int ci = idx >> 4, pos = idx & 15;
            int yy = y0 - 1 + (pos >> 2);
            int xx = x0 - 1 + (pos & 3);
            float v = 0.0f;
            if (yy >= 0 && yy < HH && xx >= 0 && xx < WW)
                v = bev[((size_t)b * CIN + ci) * (HH * WW) + (size_t)yy * WW + xx];
            win[idx] = v;
        }
        __syncthreads();

        // one wave per output channel; coalesced conv_w reads, direct
        // per-corner window reads (base, +1, +4, +5)
        const int c = cgp * 4 + wave;
        const float* wp = conv_w + (size_t)c * KW;
        float a0 = 0.f, a1 = 0.f, a2 = 0.f, a3 = 0.f;
#pragma unroll
        for (int i = 0; i < 9; ++i) {
            int k  = i * 64 + lane;
            int ci = k / 9;
            int r  = k - ci * 9;
            int ky = r / 3;
            int kx = r - ky * 3;
            int base = ci * 16 + ky * 4 + kx;
            float w = wp[k];
            a0 = fmaf(w, win[base],     a0);   // (y0,   x0)
            a1 = fmaf(w, win[base + 1], a1);   // (y0,   x0+1)
            a2 = fmaf(w, win[base + 4], a2);   // (y0+1, x0)
            a3 = fmaf(w, win[base + 5], a3);   // (y0+1, x0+1)
        }
        a0 = wave_reduce(a0);
        a1 = wave_reduce(a1);
        a2 = wave_reduce(a2);
        a3 = wave_reduce(a3);
        if (lane == 0) {
            float cb = conv_b[c];
            float v0 = fmaxf(a0 + cb, 0.0f);
            float v1 = fmaxf(a1 + cb, 0.0f);
            float v2 = fmaxf(a2 + cb, 0.0f);
            float v3 = fmaxf(a3 + cb, 0.0f);
            s_g[b * DD + c] = cw[0] * v0 + cw[1] * v1 + cw[2] * v2 + cw[3] * v3;
        }

        // aws[b]: one block per batch (block-uniform branch)
        if (cgp == 0) {
            float psx = pscore[b * 2 + 0];
            float psy = pscore[b * 2 + 1];
            float p = (tid < 128) ? psy : psx;  // concat([embed(y), embed(x)])
            int j = (tid & 127) >> 1;
            float dimt = powf(10000.0f, (float)j * (1.0f / 64.0f));
            float arg = p * 6.283185307179586f / dimt;
            float e = (tid & 1) ? cosf(arg) : sinf(arg);
            red[tid] = e * aws_w[tid];
            __syncthreads();
            for (int off = 128; off > 0; off >>= 1) {
                if (tid < off) red[tid] += red[tid + off];
                __syncthreads();
            }
            if (tid == 0) aws_g[b] = red[0] + aws_b[0];
        }
    }

    __threadfence();
    grid.sync();

    // ================= Phase 2: matvec t = aws * (out_w @ s) + out_b =====
    {
        red[tid] = s_g[b * DD + tid];
        __syncthreads();
        const int d = cgp * 4 + wave;
        const float* wp = out_w + (size_t)d * DD;
        float sum = 0.0f;
#pragma unroll
        for (int i = 0; i < 4; ++i)
            sum = fmaf(wp[i * 64 + lane], red[i * 64 + lane], sum);
        sum = wave_reduce(sum);
        if (lane == 0) t_g[b * DD + d] = aws_g[b] * sum + out_b[d];
    }

    __threadfence();
    grid.sync();

    // ================= Phase 3: out = queries + t (broadcast add) ========
    {
        const float4* t4 = (const float4*)t_g;
        const int base = blockIdx.x * TPB + tid;
#pragma unroll
        for (int k = 0; k < TOTAL4 / NTH; ++k) {  // exactly 5 iterations
            int i = base + k * NTH;
            float4 v = q4[i];
            int bb = i / (NQ * DD / 4);
            int d4 = i & (DD / 4 - 1);
            float4 tv = t4[bb * (DD / 4) + d4];
            v.x += tv.x; v.y += tv.y; v.z += tv.z; v.w += tv.w;
            out4[i] = v;
        }
    }
}

extern "C" void kernel_launch(void* const* d_in, const int* in_sizes, int n_in,
                              void* d_out, int out_size, void* d_ws, size_t ws_size,
                              hipStream_t stream) {
    const float* queries = (const float*)d_in[0];   // (B,NQ,256)
    const float* navi    = (const float*)d_in[1];   // (B,2)
    const float* bev     = (const float*)d_in[2];   // (B,64,200,200)
    // d_in[3] spatial_shape — unused (values 200,200)
    const float* pscore  = (const float*)d_in[4];   // (B,2)
    // d_in[5] aw_w, d_in[6] aw_b — dead (softmax over size-1 axis == 1)
    const float* aws_w   = (const float*)d_in[7];   // (1,256)
    const float* aws_b   = (const float*)d_in[8];   // (1,)
    const float* conv_w  = (const float*)d_in[9];   // (256,64,3,3)
    const float* conv_b  = (const float*)d_in[10];  // (256,)
    const float* out_w   = (const float*)d_in[11];  // (256,256)
    const float* out_b   = (const float*)d_in[12];  // (256,)
    const float4* q4 = (const float4*)queries;
    float4* out4 = (float4*)d_out;

    // workspace layout (floats): s[B*256] | aws[B..pad 256] | t[B*256]
    float* s   = (float*)d_ws;
    float* aws = s + BB * DD;
    float* t   = s + BB * DD + 256;                 // 16B-aligned

    void* args[] = {
        (void*)&navi, (void*)&bev, (void*)&pscore, (void*)&aws_w, (void*)&aws_b,
        (void*)&conv_w, (void*)&conv_b, (void*)&out_w, (void*)&out_b,
        (void*)&q4, (void*)&out4, (void*)&s, (void*)&aws, (void*)&t};
    hipLaunchCooperativeKernel((void*)fused_kernel, dim3(GRID), dim3(TPB),
                               args, 0, stream);
}

// Round 4
// 159.997 us; speedup vs baseline: 2.2041x; 2.2041x over previous
//
#include <hip/hip_runtime.h>
#include <math.h>

#define NQ   1280
#define DD   256
#define CIN  64
#define HH   200
#define WW   200
#define BB   8
#define KW   576                    // CIN * 9 taps per output channel
#define TPB  256
#define PER_BLK4 (NQ * DD / 4 / 64) // 1280 float4 per add-block (64 blocks/batch)

__device__ __forceinline__ float wave_reduce(float v) {
#pragma unroll
    for (int off = 32; off > 0; off >>= 1) v += __shfl_down(v, off, 64);
    return v;
}

// Kernel 1: grid = B*64 blocks, 4 waves each; one wave per conv output channel.
// s[b,c] = bilinear blend of ReLU(conv3x3(bev)[c]) at the per-batch grid point.
// cgp==0 blocks also compute aws[b] = sineembed(point_score[b]).aws_w + aws_b.
__global__ __launch_bounds__(256) void conv_sample_kernel(
    const float* __restrict__ navi,    // (B,2)
    const float* __restrict__ bev,     // (B,64,H,W)
    const float* __restrict__ pscore,  // (B,2)
    const float* __restrict__ aws_w,   // (256,)
    const float* __restrict__ aws_b,   // (1,)
    const float* __restrict__ conv_w,  // (256,64,3,3)
    const float* __restrict__ conv_b,  // (256,)
    float* __restrict__ s_out,         // ws: (B,256)
    float* __restrict__ aws_out)       // ws: (B,)
{
    const int b    = blockIdx.x >> 6;
    const int cgp  = blockIdx.x & 63;
    const int tid  = threadIdx.x;
    const int lane = tid & 63;
    const int wave = tid >> 6;

    __shared__ float win[CIN * 16];  // 4x4 zero-padded window per in-channel
    __shared__ float red[DD];        // aws reduction

    // ---- per-batch sample point ----
    float nx = navi[b * 2 + 0];
    float ny = navi[b * 2 + 1];
    float gx = (ny * (1.0f / 32.0f) + 1.0f) * 0.5f * (float)WW - 0.5f;
    float gy = (nx * (1.0f / 32.0f) + 1.0f) * 0.5f * (float)HH - 0.5f;
    float x0f = floorf(gx), y0f = floorf(gy);
    float wx1 = gx - x0f, wy1 = gy - y0f;
    int x0 = (int)x0f, y0 = (int)y0f;

    float cw[4];
    {
        float wx[2] = {1.0f - wx1, wx1};
        float wy[2] = {1.0f - wy1, wy1};
#pragma unroll
        for (int k = 0; k < 4; ++k) {
            int dx = k & 1, dy = k >> 1;
            float ixf = x0f + (float)dx, iyf = y0f + (float)dy;
            bool valid = (ixf >= 0.0f) && (ixf <= (float)(WW - 1)) &&
                         (iyf >= 0.0f) && (iyf <= (float)(HH - 1));
            cw[k] = wx[dx] * wy[dy] * (valid ? 1.0f : 0.0f);
        }
    }

    // ---- stage 4x4 zero-padded window, all 64 input channels ----
    for (int idx = tid; idx < CIN * 16; idx += TPB) {
        int ci = idx >> 4, pos = idx & 15;
        int yy = y0 - 1 + (pos >> 2);
        int xx = x0 - 1 + (pos & 3);
        float v = 0.0f;
        if (yy >= 0 && yy < HH && xx >= 0 && xx < WW)
            v = bev[((size_t)b * CIN + ci) * (HH * WW) + (size_t)yy * WW + xx];
        win[idx] = v;
    }
    __syncthreads();

    // ---- one wave per output channel; coalesced conv_w reads ----
    const int c = cgp * 4 + wave;
    const float* wp = conv_w + (size_t)c * KW;
    float a0 = 0.f, a1 = 0.f, a2 = 0.f, a3 = 0.f;
#pragma unroll
    for (int i = 0; i < 9; ++i) {
        int k  = i * 64 + lane;
        int ci = k / 9;
        int r  = k - ci * 9;
        int ky = r / 3;
        int kx = r - ky * 3;
        int base = ci * 16 + ky * 4 + kx;
        float w = wp[k];
        a0 = fmaf(w, win[base],     a0);   // (y0,   x0)
        a1 = fmaf(w, win[base + 1], a1);   // (y0,   x0+1)
        a2 = fmaf(w, win[base + 4], a2);   // (y0+1, x0)
        a3 = fmaf(w, win[base + 5], a3);   // (y0+1, x0+1)
    }
    a0 = wave_reduce(a0);
    a1 = wave_reduce(a1);
    a2 = wave_reduce(a2);
    a3 = wave_reduce(a3);
    if (lane == 0) {
        float cb = conv_b[c];
        float v0 = fmaxf(a0 + cb, 0.0f);
        float v1 = fmaxf(a1 + cb, 0.0f);
        float v2 = fmaxf(a2 + cb, 0.0f);
        float v3 = fmaxf(a3 + cb, 0.0f);
        s_out[b * DD + c] = cw[0] * v0 + cw[1] * v1 + cw[2] * v2 + cw[3] * v3;
    }

    // ---- aws[b]: one block per batch (block-uniform branch) ----
    if (cgp == 0) {
        float psx = pscore[b * 2 + 0];
        float psy = pscore[b * 2 + 1];
        float p = (tid < 128) ? psy : psx;  // concat([embed(y), embed(x)])
        int j = (tid & 127) >> 1;
        float dimt = powf(10000.0f, (float)j * (1.0f / 64.0f));
        float arg = p * 6.283185307179586f / dimt;
        float e = (tid & 1) ? cosf(arg) : sinf(arg);
        red[tid] = e * aws_w[tid];
        __syncthreads();
        for (int off = 128; off > 0; off >>= 1) {
            if (tid < off) red[tid] += red[tid + off];
            __syncthreads();
        }
        if (tid == 0) aws_out[b] = red[0] + aws_b[0];
    }
}

// Kernel 2: grid = B*64 blocks. Each block recomputes t[b,:] (out_w is
// L2-resident: 256 KB) then streams its 1280-float4 slice of
// out = queries + t. Queries are prefetched into registers before the
// matvec so the HBM latency hides the t-compute.
__global__ __launch_bounds__(256) void matvec_add_kernel(
    const float* __restrict__ out_w,   // (256,256)
    const float* __restrict__ out_b,   // (256,)
    const float* __restrict__ s_in,    // ws: (B,256)
    const float* __restrict__ aws_in,  // ws: (B,)
    const float4* __restrict__ q4,     // queries as float4
    float4* __restrict__ out4)         // output as float4
{
    const int b   = blockIdx.x >> 6;
    const int tid = threadIdx.x;

    __shared__ float s_sh[DD];
    __shared__ float t_sh[DD];

    // prefetch this block's queries slice (5 float4 per thread)
    const int base = blockIdx.x * PER_BLK4 + tid;
    float4 qv[PER_BLK4 / TPB];
#pragma unroll
    for (int k = 0; k < PER_BLK4 / TPB; ++k)   // 5 iterations
        qv[k] = q4[base + k * TPB];

    s_sh[tid] = s_in[b * DD + tid];
    float aws = aws_in[b];
    __syncthreads();

    // t[d] for d = tid: row-dot against LDS-broadcast s (out_w hot in L2)
    {
        const float4* wr = (const float4*)(out_w + (size_t)tid * DD);
        const float4* s4 = (const float4*)s_sh;
        float sum = 0.0f;
#pragma unroll
        for (int c4 = 0; c4 < DD / 4; ++c4) {
            float4 w4 = wr[c4];
            float4 sv = s4[c4];
            sum += w4.x * sv.x + w4.y * sv.y + w4.z * sv.z + w4.w * sv.w;
        }
        t_sh[tid] = aws * sum + out_b[tid];
    }
    __syncthreads();

    // out = queries + t  (d4 = flat float4 index & 63)
    const float4* t4 = (const float4*)t_sh;
#pragma unroll
    for (int k = 0; k < PER_BLK4 / TPB; ++k) {
        int i = base + k * TPB;
        float4 tv = t4[i & (DD / 4 - 1)];
        float4 v = qv[k];
        v.x += tv.x; v.y += tv.y; v.z += tv.z; v.w += tv.w;
        out4[i] = v;
    }
}

extern "C" void kernel_launch(void* const* d_in, const int* in_sizes, int n_in,
                              void* d_out, int out_size, void* d_ws, size_t ws_size,
                              hipStream_t stream) {
    const float* queries = (const float*)d_in[0];   // (B,NQ,256)
    const float* navi    = (const float*)d_in[1];   // (B,2)
    const float* bev     = (const float*)d_in[2];   // (B,64,200,200)
    // d_in[3] spatial_shape — unused (values 200,200)
    const float* pscore  = (const float*)d_in[4];   // (B,2)
    // d_in[5] aw_w, d_in[6] aw_b — dead (softmax over size-1 axis == 1)
    const float* aws_w   = (const float*)d_in[7];   // (1,256)
    const float* aws_b   = (const float*)d_in[8];   // (1,)
    const float* conv_w  = (const float*)d_in[9];   // (256,64,3,3)
    const float* conv_b  = (const float*)d_in[10];  // (256,)
    const float* out_w   = (const float*)d_in[11];  // (256,256)
    const float* out_b   = (const float*)d_in[12];  // (256,)

    // workspace layout (floats): s[B*256] | aws[B ... pad to 256]
    float* s   = (float*)d_ws;
    float* aws = s + BB * DD;

    conv_sample_kernel<<<BB * 64, TPB, 0, stream>>>(navi, bev, pscore, aws_w,
                                                    aws_b, conv_w, conv_b,
                                                    s, aws);
    matvec_add_kernel<<<BB * 64, TPB, 0, stream>>>(out_w, out_b, s, aws,
                                                   (const float4*)queries,
                                                   (float4*)d_out);
}

// Round 6
// 143.913 us; speedup vs baseline: 2.4504x; 1.1118x over previous
//
#include <hip/hip_runtime.h>
#include <math.h>

#define NQ   1280
#define DD   256
#define CIN  64
#define HH   200
#define WW   200
#define BB   8
#define KW   576   // CIN * 9 taps per output channel
#define TPB  256

typedef float floatx4 __attribute__((ext_vector_type(4)));

__device__ __forceinline__ float wave_reduce(float v) {
#pragma unroll
    for (int off = 32; off > 0; off >>= 1) v += __shfl_down(v, off, 64);
    return v;
}

// Kernel 1: grid = B*64 blocks, 4 waves each; one wave per conv output channel.
// s[b,c] = bilinear blend of ReLU(conv3x3(bev)[c]) at the per-batch grid point.
// cgp==0 blocks also compute aws[b] = sineembed(point_score[b]).aws_w + aws_b.
__global__ __launch_bounds__(256) void conv_sample_kernel(
    const float* __restrict__ navi,    // (B,2)
    const float* __restrict__ bev,     // (B,64,H,W)
    const float* __restrict__ pscore,  // (B,2)
    const float* __restrict__ aws_w,   // (256,)
    const float* __restrict__ aws_b,   // (1,)
    const float* __restrict__ conv_w,  // (256,64,3,3)
    const float* __restrict__ conv_b,  // (256,)
    float* __restrict__ s_out,         // ws: (B,256)
    float* __restrict__ aws_out)       // ws: (B,)
{
    const int b    = blockIdx.x >> 6;
    const int cgp  = blockIdx.x & 63;
    const int tid  = threadIdx.x;
    const int lane = tid & 63;
    const int wave = tid >> 6;

    __shared__ float win[CIN * 16];  // 4x4 zero-padded window per in-channel
    __shared__ float red[DD];        // aws reduction

    // ---- per-batch sample point ----
    float nx = navi[b * 2 + 0];
    float ny = navi[b * 2 + 1];
    float gx = (ny * (1.0f / 32.0f) + 1.0f) * 0.5f * (float)WW - 0.5f;
    float gy = (nx * (1.0f / 32.0f) + 1.0f) * 0.5f * (float)HH - 0.5f;
    float x0f = floorf(gx), y0f = floorf(gy);
    float wx1 = gx - x0f, wy1 = gy - y0f;
    int x0 = (int)x0f, y0 = (int)y0f;

    float cw[4];
    {
        float wx[2] = {1.0f - wx1, wx1};
        float wy[2] = {1.0f - wy1, wy1};
#pragma unroll
        for (int k = 0; k < 4; ++k) {
            int dx = k & 1, dy = k >> 1;
            float ixf = x0f + (float)dx, iyf = y0f + (float)dy;
            bool valid = (ixf >= 0.0f) && (ixf <= (float)(WW - 1)) &&
                         (iyf >= 0.0f) && (iyf <= (float)(HH - 1));
            cw[k] = wx[dx] * wy[dy] * (valid ? 1.0f : 0.0f);
        }
    }

    // ---- stage 4x4 zero-padded window, all 64 input channels ----
    for (int idx = tid; idx < CIN * 16; idx += TPB) {
        int ci = idx >> 4, pos = idx & 15;
        int yy = y0 - 1 + (pos >> 2);
        int xx = x0 - 1 + (pos & 3);
        float v = 0.0f;
        if (yy >= 0 && yy < HH && xx >= 0 && xx < WW)
            v = bev[((size_t)b * CIN + ci) * (HH * WW) + (size_t)yy * WW + xx];
        win[idx] = v;
    }
    __syncthreads();

    // ---- one wave per output channel; coalesced conv_w reads, direct
    //      per-corner window reads (base, +1, +4, +5 -> ds_read2 pairs) ----
    const int c = cgp * 4 + wave;
    const float* wp = conv_w + (size_t)c * KW;
    float a0 = 0.f, a1 = 0.f, a2 = 0.f, a3 = 0.f;
#pragma unroll
    for (int i = 0; i < 9; ++i) {
        int k  = i * 64 + lane;
        int ci = k / 9;
        int r  = k - ci * 9;
        int ky = r / 3;
        int kx = r - ky * 3;
        int base = ci * 16 + ky * 4 + kx;
        float w = wp[k];
        a0 = fmaf(w, win[base],     a0);   // (y0,   x0)
        a1 = fmaf(w, win[base + 1], a1);   // (y0,   x0+1)
        a2 = fmaf(w, win[base + 4], a2);   // (y0+1, x0)
        a3 = fmaf(w, win[base + 5], a3);   // (y0+1, x0+1)
    }
    a0 = wave_reduce(a0);
    a1 = wave_reduce(a1);
    a2 = wave_reduce(a2);
    a3 = wave_reduce(a3);
    if (lane == 0) {
        float cb = conv_b[c];
        float v0 = fmaxf(a0 + cb, 0.0f);
        float v1 = fmaxf(a1 + cb, 0.0f);
        float v2 = fmaxf(a2 + cb, 0.0f);
        float v3 = fmaxf(a3 + cb, 0.0f);
        s_out[b * DD + c] = cw[0] * v0 + cw[1] * v1 + cw[2] * v2 + cw[3] * v3;
    }

    // ---- aws[b]: one block per batch (block-uniform branch) ----
    if (cgp == 0) {
        float psx = pscore[b * 2 + 0];
        float psy = pscore[b * 2 + 1];
        float p = (tid < 128) ? psy : psx;  // concat([embed(y), embed(x)])
        int j = (tid & 127) >> 1;
        float dimt = powf(10000.0f, (float)j * (1.0f / 64.0f));
        float arg = p * 6.283185307179586f / dimt;
        float e = (tid & 1) ? cosf(arg) : sinf(arg);
        red[tid] = e * aws_w[tid];
        __syncthreads();
        for (int off = 128; off > 0; off >>= 1) {
            if (tid < off) red[tid] += red[tid + off];
            __syncthreads();
        }
        if (tid == 0) aws_out[b] = red[0] + aws_b[0];
    }
}

// Kernel 2: grid = B*64 blocks, one wave per output dim; COALESCED out_w row
// reads (each row of out_w is read exactly once per batch: 2 MB total).
// t[b,d] = aws[b] * dot(out_w[d,:], s[b,:]) + out_b[d]
__global__ __launch_bounds__(256) void matvec_kernel(
    const float* __restrict__ out_w,   // (256,256)
    const float* __restrict__ out_b,   // (256,)
    const float* __restrict__ s_in,    // ws: (B,256)
    const float* __restrict__ aws_in,  // ws: (B,)
    float* __restrict__ t_out)         // ws: (B,256)
{
    const int b    = blockIdx.x >> 6;
    const int cgp  = blockIdx.x & 63;
    const int tid  = threadIdx.x;
    const int lane = tid & 63;
    const int wave = tid >> 6;

    __shared__ float s_sh[DD];
    s_sh[tid] = s_in[b * DD + tid];
    __syncthreads();

    const int d = cgp * 4 + wave;
    const float* wp = out_w + (size_t)d * DD;
    float sum = 0.0f;
#pragma unroll
    for (int i = 0; i < 4; ++i)
        sum = fmaf(wp[i * 64 + lane], s_sh[i * 64 + lane], sum);
    sum = wave_reduce(sum);
    if (lane == 0) t_out[b * DD + d] = aws_in[b] * sum + out_b[d];
}

// Kernel 3: out[b,q,d] = queries[b,q,d] + t[b,d].
// 2560 blocks x 256 threads x 1 float4 — max MLP; non-temporal on the
// streaming tensors (no reuse), t broadcast via L1/L2.
__global__ __launch_bounds__(256) void add_kernel(
    const floatx4* __restrict__ q4,
    const floatx4* __restrict__ t4,   // ws: (B, 64) floatx4
    floatx4* __restrict__ out4)
{
    const int i = blockIdx.x * TPB + threadIdx.x;   // exact: grid*TPB == total4
    floatx4 v = __builtin_nontemporal_load(&q4[i]);
    const int b  = i / (NQ * DD / 4);
    const int d4 = i & (DD / 4 - 1);
    floatx4 tv = t4[b * (DD / 4) + d4];
    v += tv;
    __builtin_nontemporal_store(v, &out4[i]);
}

extern "C" void kernel_launch(void* const* d_in, const int* in_sizes, int n_in,
                              void* d_out, int out_size, void* d_ws, size_t ws_size,
                              hipStream_t stream) {
    const float* queries = (const float*)d_in[0];   // (B,NQ,256)
    const float* navi    = (const float*)d_in[1];   // (B,2)
    const float* bev     = (const float*)d_in[2];   // (B,64,200,200)
    // d_in[3] spatial_shape — unused (values 200,200)
    const float* pscore  = (const float*)d_in[4];   // (B,2)
    // d_in[5] aw_w, d_in[6] aw_b — dead (softmax over size-1 axis == 1)
    const float* aws_w   = (const float*)d_in[7];   // (1,256)
    const float* aws_b   = (const float*)d_in[8];   // (1,)
    const float* conv_w  = (const float*)d_in[9];   // (256,64,3,3)
    const float* conv_b  = (const float*)d_in[10];  // (256,)
    const float* out_w   = (const float*)d_in[11];  // (256,256)
    const float* out_b   = (const float*)d_in[12];  // (256,)

    // workspace layout (floats): s[B*256] | aws[B ... pad to 256] | t[B*256]
    float* s   = (float*)d_ws;
    float* aws = s + BB * DD;
    float* t   = s + BB * DD + 256;                 // 16B-aligned

    conv_sample_kernel<<<BB * 64, TPB, 0, stream>>>(navi, bev, pscore, aws_w,
                                                    aws_b, conv_w, conv_b,
                                                    s, aws);
    matvec_kernel<<<BB * 64, TPB, 0, stream>>>(out_w, out_b, s, aws, t);

    const int total4 = BB * NQ * DD / 4;            // 655360
    add_kernel<<<total4 / TPB, TPB, 0, stream>>>((const floatx4*)queries,
                                                 (const floatx4*)t,
                                                 (floatx4*)d_out);
}